// Round 3
// baseline (94.351 us; speedup 1.0000x reference)
//
#include <hip/hip_runtime.h>
#include <hip/hip_bf16.h>
#include <math.h>

typedef short bf16x8 __attribute__((ext_vector_type(8)));
typedef float f32x4 __attribute__((ext_vector_type(4)));
typedef unsigned int u32;
typedef unsigned short u16;

constexpr int Bb = 8, LQn = 1024, LKn = 1024, En = 512, Hn = 8, Dn = 64;
constexpr int Mtok = Bb * LQn;  // 8192
constexpr float SCALE = 0.04419417382415922f;  // 1/sqrt(512)

__device__ __forceinline__ u16 f2bf(float f) {
  u32 u = __builtin_bit_cast(u32, f);
  u32 r = (u + 0x7fffu + ((u >> 16) & 1u)) >> 16;
  return (u16)r;
}
__device__ __forceinline__ float bf2f(u16 h) {
  u32 u = ((u32)h) << 16;
  return __builtin_bit_cast(float, u);
}

// async 16B global -> LDS copy (wave-uniform LDS base + lane*16 required)
__device__ __forceinline__ void async_lds16(const void* gsrc, void* ldst) {
  __builtin_amdgcn_global_load_lds(
      (const __attribute__((address_space(1))) u32*)gsrc,
      (__attribute__((address_space(3))) u32*)ldst, 16, 0, 0);
}

// ---------------- fused fp32->bf16 + sin(|row-sum|) mask ----------------
__global__ void cvtmask_kernel(const float* __restrict__ x, u16* __restrict__ xb,
                               float* __restrict__ mask) {
  int row = blockIdx.x * 4 + (threadIdx.x >> 6);
  int lane = threadIdx.x & 63;
  const float4* p = reinterpret_cast<const float4*>(x + (size_t)row * En);
  ushort4* ob = reinterpret_cast<ushort4*>(xb + (size_t)row * En);
  double s = 0.0;
#pragma unroll
  for (int j = 0; j < En / 256; ++j) {
    float4 v = p[lane + j * 64];
    s += (double)v.x + (double)v.y + (double)v.z + (double)v.w;
    ushort4 o;
    o.x = f2bf(v.x); o.y = f2bf(v.y); o.z = f2bf(v.z); o.w = f2bf(v.w);
    ob[lane + j * 64] = o;
  }
#pragma unroll
  for (int off = 32; off > 0; off >>= 1) s += __shfl_down(s, off, 64);
  if (lane == 0) mask[row] = (float)sin(fabs(s));
}

// ---------------- 3 weight matrices fp32 -> bf16 in one launch ----------------
__global__ void cvt3_kernel(const float* __restrict__ a, const float* __restrict__ b,
                            const float* __restrict__ c, u16* __restrict__ oa,
                            u16* __restrict__ ob, u16* __restrict__ oc, int n4) {
  int i = blockIdx.x * blockDim.x + threadIdx.x;
  const float* src;
  u16* dst;
  int j = i;
  if (j < n4) { src = a; dst = oa; }
  else if (j < 2 * n4) { src = b; dst = ob; j -= n4; }
  else { src = c; dst = oc; j -= 2 * n4; }
  float4 v = reinterpret_cast<const float4*>(src)[j];
  ushort4 o;
  o.x = f2bf(v.x); o.y = f2bf(v.y); o.z = f2bf(v.z); o.w = f2bf(v.w);
  reinterpret_cast<ushort4*>(dst)[j] = o;
}

// ---------------- GEMM: C = relu(A * Bm^T + bias), bf16 out, 2-phase dbuf ----
// XROW=1: blockIdx.x = row-block (A-panel reuse stays on one XCD).
// XROW=0: blockIdx.x = col-block (B-panel reuse stays on one XCD).
template <int BIAS_ROW, int XROW>
__global__ __launch_bounds__(256, 2) void gemm_bt_relu(
    const u16* __restrict__ A, const u16* __restrict__ Bm,
    const float* __restrict__ bias, u16* __restrict__ C,
    int ldc) {
  constexpr int K = 512, BM = 128, BN = 64, BK = 64;
  __shared__ u16 sA[2][BM * BK];
  __shared__ u16 sB[2][BN * BK];
  int tid = threadIdx.x;
  int lane = tid & 63;
  int w = tid >> 6;
  int row0 = (XROW ? blockIdx.x : blockIdx.y) * BM;
  int col0 = (XROW ? blockIdx.y : blockIdx.x) * BN;
  int wm = w >> 1, wn = w & 1;
  int rgrp = lane >> 4, cidx = lane & 15;

  f32x4 acc[4][2];
#pragma unroll
  for (int mi = 0; mi < 4; ++mi)
#pragma unroll
    for (int ni = 0; ni < 2; ++ni) acc[mi][ni] = f32x4{0.f, 0.f, 0.f, 0.f};

  auto stage = [&](int kt, int buf) {
    int k0 = kt * BK;
#pragma unroll
    for (int rr = 0; rr < 4; ++rr) {  // A tile: 128x64 bf16 = 1024 16B chunks
      int cid = rr * 256 + tid;
      int r = cid >> 3, c = cid & 7;
      int cg = c ^ (r & 7);
      async_lds16(A + (size_t)(row0 + r) * K + k0 + cg * 8, &sA[buf][cid * 8]);
    }
#pragma unroll
    for (int rr = 0; rr < 2; ++rr) {  // B tile: 64x64 bf16 = 512 chunks
      int cid = rr * 256 + tid;
      int r = cid >> 3, c = cid & 7;
      int cg = c ^ (r & 7);
      async_lds16(Bm + (size_t)(col0 + r) * K + k0 + cg * 8, &sB[buf][cid * 8]);
    }
  };

  stage(0, 0);
  __syncthreads();  // drains stage(0)

  for (int kt = 0; kt < K / BK; ++kt) {
    int cur = kt & 1;
    if (kt < K / BK - 1) stage(kt + 1, cur ^ 1);  // issue next-tile loads first
#pragma unroll
    for (int kk = 0; kk < 2; ++kk) {
      bf16x8 a[4], b[2];
#pragma unroll
      for (int mi = 0; mi < 4; ++mi) {
        int row = wm * 64 + mi * 16 + cidx;
        a[mi] = *reinterpret_cast<const bf16x8*>(
            &sA[cur][row * BK + ((kk * 4 + rgrp) ^ (row & 7)) * 8]);
      }
#pragma unroll
      for (int ni = 0; ni < 2; ++ni) {
        int row = wn * 32 + ni * 16 + cidx;
        b[ni] = *reinterpret_cast<const bf16x8*>(
            &sB[cur][row * BK + ((kk * 4 + rgrp) ^ (row & 7)) * 8]);
      }
#pragma unroll
      for (int mi = 0; mi < 4; ++mi)
#pragma unroll
        for (int ni = 0; ni < 2; ++ni)
          acc[mi][ni] = __builtin_amdgcn_mfma_f32_16x16x32_bf16(a[mi], b[ni], acc[mi][ni], 0, 0, 0);
    }
    __syncthreads();  // implicit vmcnt(0) drain lands AFTER compute
  }
  // epilogue: bias + relu + bf16 store. C/D layout: col=lane&15, row=(lane>>4)*4+r
#pragma unroll
  for (int mi = 0; mi < 4; ++mi)
#pragma unroll
    for (int ni = 0; ni < 2; ++ni)
#pragma unroll
      for (int r = 0; r < 4; ++r) {
        int grow = row0 + wm * 64 + mi * 16 + rgrp * 4 + r;
        int gcol = col0 + wn * 32 + ni * 16 + cidx;
        float v = acc[mi][ni][r] + (BIAS_ROW ? bias[grow] : bias[gcol]);
        v = v > 0.f ? v : 0.f;
        C[(size_t)grow * ldc + gcol] = f2bf(v);
      }
}

// ---------------- fused masked attention, 2-phase K/V double-buffer ----------------
// grid: (B*H, LQ/64) -> all q-blocks of one (b,h) share an XCD (L2 K/V reuse).
// q,k >= 0 (ReLU) => scores in [0,~1]: no max tracking; masked keys give exact 0.
__global__ __launch_bounds__(256, 2) void attn_kernel(
    const u16* __restrict__ qb, const u16* __restrict__ kb, const u16* __restrict__ vtb,
    const float* __restrict__ kmask, const float* __restrict__ qmask,
    float* __restrict__ out) {
  __shared__ u16 sQ[64 * 64];
  __shared__ u16 sP[64 * 64];       // wave-private 16x64 slices
  __shared__ u16 sK[2][64 * 64];
  __shared__ u16 sV[2][64 * 64];    // V^T tile: rows=d (64), cols=k (64)
  int tid = threadIdx.x, lane = tid & 63, w = tid >> 6;
  int bh = blockIdx.x, qblk = blockIdx.y;
  int b = bh >> 3, h = bh & 7;
  int rgrp = lane >> 4, cidx = lane & 15;

  const u16* qbase = qb + ((size_t)(b * LQn) + qblk * 64) * En + h * Dn;
  const u16* kbase = kb + (size_t)(b * LKn) * En + h * Dn;
  const u16* vbase = vtb + (size_t)(h * Dn) * Mtok + b * LKn;
  const float* kmb = kmask + b * LKn;

  auto stageKV = [&](int kt, int buf) {
#pragma unroll
    for (int rr = 0; rr < 2; ++rr) {
      int cid = rr * 256 + tid;
      int r = cid >> 3, c = cid & 7;
      int cg = c ^ (r & 7);
      async_lds16(kbase + (size_t)(kt * 64 + r) * En + cg * 8, &sK[buf][cid * 8]);
      async_lds16(vbase + (size_t)r * Mtok + kt * 64 + cg * 8, &sV[buf][cid * 8]);
    }
  };

#pragma unroll
  for (int rr = 0; rr < 2; ++rr) {  // Q tile 64x64
    int cid = rr * 256 + tid;
    int r = cid >> 3, c = cid & 7;
    int cg = c ^ (r & 7);
    async_lds16(qbase + (size_t)r * En + cg * 8, &sQ[cid * 8]);
  }
  stageKV(0, 0);
  __syncthreads();

  bf16x8 qa[2];
  {
    int row = w * 16 + cidx;
    qa[0] = *reinterpret_cast<const bf16x8*>(&sQ[row * 64 + (rgrp ^ (row & 7)) * 8]);
    qa[1] = *reinterpret_cast<const bf16x8*>(&sQ[row * 64 + ((4 + rgrp) ^ (row & 7)) * 8]);
  }

  f32x4 acc_o[4];
#pragma unroll
  for (int dt = 0; dt < 4; ++dt) acc_o[dt] = f32x4{0.f, 0.f, 0.f, 0.f};
  float den[4] = {0.f, 0.f, 0.f, 0.f};

  for (int kt = 0; kt < LKn / 64; ++kt) {
    int cur = kt & 1;
    if (kt < LKn / 64 - 1) stageKV(kt + 1, cur ^ 1);  // prefetch before compute
    // S = Q K^T (per-wave 16x64), then P = mask ? 0 : exp(S*scale) -> bf16 LDS
#pragma unroll
    for (int ktile = 0; ktile < 4; ++ktile) {
      int krow = ktile * 16 + cidx;
      bf16x8 kf0 = *reinterpret_cast<const bf16x8*>(
          &sK[cur][krow * 64 + (rgrp ^ (krow & 7)) * 8]);
      bf16x8 kf1 = *reinterpret_cast<const bf16x8*>(
          &sK[cur][krow * 64 + ((4 + rgrp) ^ (krow & 7)) * 8]);
      f32x4 s = f32x4{0.f, 0.f, 0.f, 0.f};
      s = __builtin_amdgcn_mfma_f32_16x16x32_bf16(qa[0], kf0, s, 0, 0, 0);
      s = __builtin_amdgcn_mfma_f32_16x16x32_bf16(qa[1], kf1, s, 0, 0, 0);
      float km = kmb[kt * 64 + ktile * 16 + cidx];
      bool on = km > 0.f;
#pragma unroll
      for (int r = 0; r < 4; ++r) {
        float p = on ? __expf(s[r] * SCALE) : 0.f;
        u16 pb = f2bf(p);
        den[r] += bf2f(pb);  // denominator consistent with bf16 numerator
        int prow = w * 16 + rgrp * 4 + r;
        sP[prow * 64 + ((ktile * 16 + cidx) ^ ((prow & 7) << 3))] = pb;
      }
    }
    // PV: out(16q x 64d) += P(16q x 64k) * V(64k x 64d); wave-private P, no barrier
#pragma unroll
    for (int kk = 0; kk < 2; ++kk) {
      int prow = w * 16 + cidx;
      bf16x8 pa = *reinterpret_cast<const bf16x8*>(
          &sP[prow * 64 + ((kk * 4 + rgrp) ^ (prow & 7)) * 8]);
#pragma unroll
      for (int dt = 0; dt < 4; ++dt) {
        int vrow = dt * 16 + cidx;
        bf16x8 vf = *reinterpret_cast<const bf16x8*>(
            &sV[cur][vrow * 64 + ((kk * 4 + rgrp) ^ (vrow & 7)) * 8]);
        acc_o[dt] = __builtin_amdgcn_mfma_f32_16x16x32_bf16(pa, vf, acc_o[dt], 0, 0, 0);
      }
    }
    __syncthreads();  // drain (covers next-tile prefetch) after full compute phase
  }
  // reduce denominators across the 16 lanes sharing the same rows
#pragma unroll
  for (int r = 0; r < 4; ++r)
#pragma unroll
    for (int off = 8; off > 0; off >>= 1) den[r] += __shfl_xor(den[r], off, 64);

  const float* qmb = qmask + (size_t)b * LQn + qblk * 64 + w * 16;
  const u16* qres = qbase + (size_t)(w * 16) * En;
  float* obase = out + ((size_t)(b * LQn) + qblk * 64 + w * 16) * En + h * Dn;
#pragma unroll
  for (int r = 0; r < 4; ++r) {
    int qr = rgrp * 4 + r;
    float fac = qmb[qr] / den[r];
#pragma unroll
    for (int dt = 0; dt < 4; ++dt) {
      float v = acc_o[dt][r] * fac + bf2f(qres[(size_t)qr * En + dt * 16 + cidx]);
      obase[(size_t)qr * En + dt * 16 + cidx] = v;
    }
  }
}

extern "C" void kernel_launch(void* const* d_in, const int* in_sizes, int n_in,
                              void* d_out, int out_size, void* d_ws, size_t ws_size,
                              hipStream_t stream) {
  const float* x1 = (const float*)d_in[0];
  const float* x2 = (const float*)d_in[1];
  const float* Wq = (const float*)d_in[2];
  const float* bq = (const float*)d_in[3];
  const float* Wk = (const float*)d_in[4];
  const float* bk = (const float*)d_in[5];
  const float* Wv = (const float*)d_in[6];
  const float* bv = (const float*)d_in[7];
  float* out = (float*)d_out;

  char* ws = (char*)d_ws;
  size_t o = 0;
  u16* x1b = (u16*)(ws + o); o += (size_t)Mtok * En * 2;
  u16* x2b = (u16*)(ws + o); o += (size_t)Mtok * En * 2;
  u16* wqb = (u16*)(ws + o); o += (size_t)En * En * 2;
  u16* wkb = (u16*)(ws + o); o += (size_t)En * En * 2;
  u16* wvb = (u16*)(ws + o); o += (size_t)En * En * 2;
  u16* qbq = (u16*)(ws + o); o += (size_t)Mtok * En * 2;
  u16* kbk = (u16*)(ws + o); o += (size_t)Mtok * En * 2;
  u16* vtb = (u16*)(ws + o); o += (size_t)Mtok * En * 2;  // [E][Mtok] transposed
  float* kmask = (float*)(ws + o); o += (size_t)Mtok * 4;
  float* qmask = (float*)(ws + o); o += (size_t)Mtok * 4;

  cvtmask_kernel<<<Mtok / 4, 256, 0, stream>>>(x1, x1b, qmask);
  cvtmask_kernel<<<Mtok / 4, 256, 0, stream>>>(x2, x2b, kmask);

  int n4w = En * En / 4;  // 65536
  cvt3_kernel<<<3 * n4w / 256, 256, 0, stream>>>(Wq, Wk, Wv, wqb, wkb, wvb, n4w);

  dim3 gq(Mtok / 128, En / 64);  // x=row-block (64), y=col-block (8)
  gemm_bt_relu<0, 1><<<gq, 256, 0, stream>>>(x1b, wqb, bq, qbq, En);
  gemm_bt_relu<0, 1><<<gq, 256, 0, stream>>>(x2b, wkb, bk, kbk, En);
  dim3 gv(Mtok / 64, En / 128);  // x=col-block (128), y=row-block (4)
  gemm_bt_relu<1, 0><<<gv, 256, 0, stream>>>(wvb, x2b, bv, vtb, Mtok);

  dim3 ga(Bb * Hn, LQn / 64);  // x=bh (64), y=qblk (16)
  attn_kernel<<<ga, 256, 0, stream>>>(qbq, kbk, vtb, kmask, qmask, out);
}

// Round 4
// 78.463 us; speedup vs baseline: 1.2025x; 1.2025x over previous
//
#include <hip/hip_runtime.h>
#include <hip/hip_bf16.h>
#include <math.h>

typedef short bf16x8 __attribute__((ext_vector_type(8)));
typedef float f32x4 __attribute__((ext_vector_type(4)));
typedef unsigned int u32;
typedef unsigned short u16;

constexpr int Bb = 8, LQn = 1024, LKn = 1024, En = 512, Hn = 8, Dn = 64;
constexpr int Mtok = Bb * LQn;  // 8192
// 1/sqrt(512) * log2(e): folded into K so softmax is a bare exp2
constexpr float KCOEF = 0.06376246332977306f;

__device__ __forceinline__ u16 f2bf(float f) {
  u32 u = __builtin_bit_cast(u32, f);
  u32 r = (u + 0x7fffu + ((u >> 16) & 1u)) >> 16;
  return (u16)r;
}
__device__ __forceinline__ float bf2f(u16 h) {
  u32 u = ((u32)h) << 16;
  return __builtin_bit_cast(float, u);
}
__device__ __forceinline__ u16 f2bf_hw(float f) {
  return __builtin_bit_cast(u16, __float2bfloat16(f));
}

// async 16B global -> LDS copy (wave-uniform LDS base + lane*16 required)
__device__ __forceinline__ void async_lds16(const void* gsrc, void* ldst) {
  __builtin_amdgcn_global_load_lds(
      (const __attribute__((address_space(1))) u32*)gsrc,
      (__attribute__((address_space(3))) u32*)ldst, 16, 0, 0);
}

// ------------- fused fp32->bf16 + sin(|row-sum|) masks, x1 and x2 in one launch -------------
__global__ void cvtmask2_kernel(const float* __restrict__ x1, const float* __restrict__ x2,
                                u16* __restrict__ x1b, u16* __restrict__ x2b,
                                float* __restrict__ qmask, float* __restrict__ kmask) {
  int id = blockIdx.x * 4 + (threadIdx.x >> 6);
  int lane = threadIdx.x & 63;
  const float* x; u16* xb; float* mask; int row;
  if (id < Mtok) { x = x1; xb = x1b; mask = qmask; row = id; }
  else           { x = x2; xb = x2b; mask = kmask; row = id - Mtok; }
  const float4* p = reinterpret_cast<const float4*>(x + (size_t)row * En);
  ushort4* ob = reinterpret_cast<ushort4*>(xb + (size_t)row * En);
  double s = 0.0;
#pragma unroll
  for (int j = 0; j < En / 256; ++j) {
    float4 v = p[lane + j * 64];
    s += (double)v.x + (double)v.y + (double)v.z + (double)v.w;
    ushort4 o;
    o.x = f2bf(v.x); o.y = f2bf(v.y); o.z = f2bf(v.z); o.w = f2bf(v.w);
    ob[lane + j * 64] = o;
  }
#pragma unroll
  for (int off = 32; off > 0; off >>= 1) s += __shfl_down(s, off, 64);
  if (lane == 0) mask[row] = (float)sin(fabs(s));
}

// ---------------- 3 weight matrices fp32 -> bf16 in one launch ----------------
__global__ void cvt3_kernel(const float* __restrict__ a, const float* __restrict__ b,
                            const float* __restrict__ c, u16* __restrict__ oa,
                            u16* __restrict__ ob, u16* __restrict__ oc, int n4) {
  int i = blockIdx.x * blockDim.x + threadIdx.x;
  const float* src;
  u16* dst;
  int j = i;
  if (j < n4) { src = a; dst = oa; }
  else if (j < 2 * n4) { src = b; dst = ob; j -= n4; }
  else { src = c; dst = oc; j -= 2 * n4; }
  float4 v = reinterpret_cast<const float4*>(src)[j];
  ushort4 o;
  o.x = f2bf(v.x); o.y = f2bf(v.y); o.z = f2bf(v.z); o.w = f2bf(v.w);
  reinterpret_cast<ushort4*>(dst)[j] = o;
}

// ---------------- GEMM: C = coef * relu(A * Bm^T + bias), bf16 out, 2-phase dbuf ----
template <int BIAS_ROW, int XROW>
__global__ __launch_bounds__(256, 2) void gemm_bt_relu(
    const u16* __restrict__ A, const u16* __restrict__ Bm,
    const float* __restrict__ bias, u16* __restrict__ C,
    int ldc, float coef) {
  constexpr int K = 512, BM = 128, BN = 64, BK = 64;
  __shared__ u16 sA[2][BM * BK];
  __shared__ u16 sB[2][BN * BK];
  int tid = threadIdx.x;
  int lane = tid & 63;
  int w = tid >> 6;
  int row0 = (XROW ? blockIdx.x : blockIdx.y) * BM;
  int col0 = (XROW ? blockIdx.y : blockIdx.x) * BN;
  int wm = w >> 1, wn = w & 1;
  int rgrp = lane >> 4, cidx = lane & 15;

  f32x4 acc[4][2];
#pragma unroll
  for (int mi = 0; mi < 4; ++mi)
#pragma unroll
    for (int ni = 0; ni < 2; ++ni) acc[mi][ni] = f32x4{0.f, 0.f, 0.f, 0.f};

  auto stage = [&](int kt, int buf) {
    int k0 = kt * BK;
#pragma unroll
    for (int rr = 0; rr < 4; ++rr) {  // A tile: 128x64 bf16 = 1024 16B chunks
      int cid = rr * 256 + tid;
      int r = cid >> 3, c = cid & 7;
      int cg = c ^ (r & 7);
      async_lds16(A + (size_t)(row0 + r) * K + k0 + cg * 8, &sA[buf][cid * 8]);
    }
#pragma unroll
    for (int rr = 0; rr < 2; ++rr) {  // B tile: 64x64 bf16 = 512 chunks
      int cid = rr * 256 + tid;
      int r = cid >> 3, c = cid & 7;
      int cg = c ^ (r & 7);
      async_lds16(Bm + (size_t)(col0 + r) * K + k0 + cg * 8, &sB[buf][cid * 8]);
    }
  };

  stage(0, 0);
  __syncthreads();  // drains stage(0)

  for (int kt = 0; kt < K / BK; ++kt) {
    int cur = kt & 1;
    if (kt < K / BK - 1) stage(kt + 1, cur ^ 1);  // issue next-tile loads first
#pragma unroll
    for (int kk = 0; kk < 2; ++kk) {
      bf16x8 a[4], b[2];
#pragma unroll
      for (int mi = 0; mi < 4; ++mi) {
        int row = wm * 64 + mi * 16 + cidx;
        a[mi] = *reinterpret_cast<const bf16x8*>(
            &sA[cur][row * BK + ((kk * 4 + rgrp) ^ (row & 7)) * 8]);
      }
#pragma unroll
      for (int ni = 0; ni < 2; ++ni) {
        int row = wn * 32 + ni * 16 + cidx;
        b[ni] = *reinterpret_cast<const bf16x8*>(
            &sB[cur][row * BK + ((kk * 4 + rgrp) ^ (row & 7)) * 8]);
      }
#pragma unroll
      for (int mi = 0; mi < 4; ++mi)
#pragma unroll
        for (int ni = 0; ni < 2; ++ni)
          acc[mi][ni] = __builtin_amdgcn_mfma_f32_16x16x32_bf16(a[mi], b[ni], acc[mi][ni], 0, 0, 0);
    }
    __syncthreads();  // implicit vmcnt(0) drain lands AFTER compute
  }
  // epilogue: bias + relu + coef + bf16 store. C/D layout: col=lane&15, row=(lane>>4)*4+r
#pragma unroll
  for (int mi = 0; mi < 4; ++mi)
#pragma unroll
    for (int ni = 0; ni < 2; ++ni)
#pragma unroll
      for (int r = 0; r < 4; ++r) {
        int grow = row0 + wm * 64 + mi * 16 + rgrp * 4 + r;
        int gcol = col0 + wn * 32 + ni * 16 + cidx;
        float v = acc[mi][ni][r] + (BIAS_ROW ? bias[grow] : bias[gcol]);
        v = v > 0.f ? v : 0.f;
        C[(size_t)grow * ldc + gcol] = f2bf(v * coef);
      }
}

// ---------------- fused masked attention, dbuf K/V + unioned Q/P LDS ----------------
// grid: (B*H, LQ/64) -> all q-blocks of one (b,h) share an XCD (L2 K/V reuse).
// K was pre-scaled by 1/sqrt(E)*log2(e) at its GEMM epilogue: softmax is bare exp2.
// LDS 40KB -> 4 blocks/CU. sQP: each wave's Q-frag bytes == its private P-slice
// (Q consumed into regs before first P write; same array => compiler keeps order).
__global__ __launch_bounds__(256, 4) void attn_kernel(
    const u16* __restrict__ qb, const u16* __restrict__ kb, const u16* __restrict__ vtb,
    const float* __restrict__ kmask, const float* __restrict__ qmask,
    float* __restrict__ out) {
  __shared__ u16 sK[2][64 * 64];
  __shared__ u16 sV[2][64 * 64];    // V^T tile: rows=d (64), cols=k (64)
  __shared__ u16 sQP[64 * 64];      // Q tile, then wave-private 16x64 P slices
  int tid = threadIdx.x, lane = tid & 63, w = tid >> 6;
  int bh = blockIdx.x, qblk = blockIdx.y;
  int b = bh >> 3, h = bh & 7;
  int rgrp = lane >> 4, cidx = lane & 15;

  const u16* qbase = qb + ((size_t)(b * LQn) + qblk * 64) * En + h * Dn;
  const u16* kbase = kb + (size_t)(b * LKn) * En + h * Dn;
  const u16* vbase = vtb + (size_t)(h * Dn) * Mtok + b * LKn;
  const float* kmb = kmask + b * LKn;

  auto stageKV = [&](int kt, int buf) {
#pragma unroll
    for (int rr = 0; rr < 2; ++rr) {
      int cid = rr * 256 + tid;
      int r = cid >> 3, c = cid & 7;
      int cg = c ^ (r & 7);
      async_lds16(kbase + (size_t)(kt * 64 + r) * En + cg * 8, &sK[buf][cid * 8]);
      async_lds16(vbase + (size_t)r * Mtok + kt * 64 + cg * 8, &sV[buf][cid * 8]);
    }
  };

#pragma unroll
  for (int rr = 0; rr < 2; ++rr) {  // Q tile 64x64 into sQP
    int cid = rr * 256 + tid;
    int r = cid >> 3, c = cid & 7;
    int cg = c ^ (r & 7);
    async_lds16(qbase + (size_t)r * En + cg * 8, &sQP[cid * 8]);
  }
  stageKV(0, 0);
  __syncthreads();

  bf16x8 qa[2];
  {
    int row = w * 16 + cidx;
    qa[0] = *reinterpret_cast<const bf16x8*>(&sQP[row * 64 + (rgrp ^ (row & 7)) * 8]);
    qa[1] = *reinterpret_cast<const bf16x8*>(&sQP[row * 64 + ((4 + rgrp) ^ (row & 7)) * 8]);
  }

  f32x4 acc_o[4];
#pragma unroll
  for (int dt = 0; dt < 4; ++dt) acc_o[dt] = f32x4{0.f, 0.f, 0.f, 0.f};
  float den[4] = {0.f, 0.f, 0.f, 0.f};

  for (int kt = 0; kt < LKn / 64; ++kt) {
    int cur = kt & 1;
    if (kt < LKn / 64 - 1) stageKV(kt + 1, cur ^ 1);  // prefetch before compute
    // S = Q K^T (per-wave 16x64), P = mask ? 0 : exp2(S) -> bf16 LDS
#pragma unroll
    for (int ktile = 0; ktile < 4; ++ktile) {
      int krow = ktile * 16 + cidx;
      bf16x8 kf0 = *reinterpret_cast<const bf16x8*>(
          &sK[cur][krow * 64 + (rgrp ^ (krow & 7)) * 8]);
      bf16x8 kf1 = *reinterpret_cast<const bf16x8*>(
          &sK[cur][krow * 64 + ((4 + rgrp) ^ (krow & 7)) * 8]);
      f32x4 s = f32x4{0.f, 0.f, 0.f, 0.f};
      s = __builtin_amdgcn_mfma_f32_16x16x32_bf16(qa[0], kf0, s, 0, 0, 0);
      s = __builtin_amdgcn_mfma_f32_16x16x32_bf16(qa[1], kf1, s, 0, 0, 0);
      float km = kmb[kt * 64 + ktile * 16 + cidx];
      bool on = km > 0.f;
#pragma unroll
      for (int r = 0; r < 4; ++r) {
        float p = on ? __builtin_amdgcn_exp2f(s[r]) : 0.f;
        den[r] += p;  // fp32 denominator (pre-rounding; <=2^-9 rel inconsistency)
        int prow = w * 16 + rgrp * 4 + r;
        sQP[prow * 64 + ((ktile * 16 + cidx) ^ ((prow & 7) << 3))] = f2bf_hw(p);
      }
    }
    // PV: out(16q x 64d) += P(16q x 64k) * V(64k x 64d); wave-private P, no barrier
#pragma unroll
    for (int kk = 0; kk < 2; ++kk) {
      int prow = w * 16 + cidx;
      bf16x8 pa = *reinterpret_cast<const bf16x8*>(
          &sQP[prow * 64 + ((kk * 4 + rgrp) ^ (prow & 7)) * 8]);
#pragma unroll
      for (int dt = 0; dt < 4; ++dt) {
        int vrow = dt * 16 + cidx;
        bf16x8 vf = *reinterpret_cast<const bf16x8*>(
            &sV[cur][vrow * 64 + ((kk * 4 + rgrp) ^ (vrow & 7)) * 8]);
        acc_o[dt] = __builtin_amdgcn_mfma_f32_16x16x32_bf16(pa, vf, acc_o[dt], 0, 0, 0);
      }
    }
    __syncthreads();  // drain (covers next-tile prefetch) after full compute phase
  }
  // reduce denominators across the 16 lanes sharing the same rows
#pragma unroll
  for (int r = 0; r < 4; ++r)
#pragma unroll
    for (int off = 8; off > 0; off >>= 1) den[r] += __shfl_xor(den[r], off, 64);

  const float* qmb = qmask + (size_t)b * LQn + qblk * 64 + w * 16;
  const u16* qres = qbase + (size_t)(w * 16) * En;
  float* obase = out + ((size_t)(b * LQn) + qblk * 64 + w * 16) * En + h * Dn;
#pragma unroll
  for (int r = 0; r < 4; ++r) {
    int qr = rgrp * 4 + r;
    float fac = qmb[qr] / den[r];
#pragma unroll
    for (int dt = 0; dt < 4; ++dt) {
      float v = acc_o[dt][r] * fac + bf2f(qres[(size_t)qr * En + dt * 16 + cidx]);
      obase[(size_t)qr * En + dt * 16 + cidx] = v;
    }
  }
}

extern "C" void kernel_launch(void* const* d_in, const int* in_sizes, int n_in,
                              void* d_out, int out_size, void* d_ws, size_t ws_size,
                              hipStream_t stream) {
  const float* x1 = (const float*)d_in[0];
  const float* x2 = (const float*)d_in[1];
  const float* Wq = (const float*)d_in[2];
  const float* bq = (const float*)d_in[3];
  const float* Wk = (const float*)d_in[4];
  const float* bk = (const float*)d_in[5];
  const float* Wv = (const float*)d_in[6];
  const float* bv = (const float*)d_in[7];
  float* out = (float*)d_out;

  char* ws = (char*)d_ws;
  size_t o = 0;
  u16* x1b = (u16*)(ws + o); o += (size_t)Mtok * En * 2;
  u16* x2b = (u16*)(ws + o); o += (size_t)Mtok * En * 2;
  u16* wqb = (u16*)(ws + o); o += (size_t)En * En * 2;
  u16* wkb = (u16*)(ws + o); o += (size_t)En * En * 2;
  u16* wvb = (u16*)(ws + o); o += (size_t)En * En * 2;
  u16* qbq = (u16*)(ws + o); o += (size_t)Mtok * En * 2;
  u16* kbk = (u16*)(ws + o); o += (size_t)Mtok * En * 2;
  u16* vtb = (u16*)(ws + o); o += (size_t)Mtok * En * 2;  // [E][Mtok] transposed
  float* kmask = (float*)(ws + o); o += (size_t)Mtok * 4;
  float* qmask = (float*)(ws + o); o += (size_t)Mtok * 4;

  cvtmask2_kernel<<<2 * Mtok / 4, 256, 0, stream>>>(x1, x2, x1b, x2b, qmask, kmask);

  int n4w = En * En / 4;  // 65536
  cvt3_kernel<<<3 * n4w / 256, 256, 0, stream>>>(Wq, Wk, Wv, wqb, wkb, wvb, n4w);

  dim3 gq(Mtok / 128, En / 64);  // x=row-block (64), y=col-block (8)
  gemm_bt_relu<0, 1><<<gq, 256, 0, stream>>>(x1b, wqb, bq, qbq, En, 1.0f);
  gemm_bt_relu<0, 1><<<gq, 256, 0, stream>>>(x2b, wkb, bk, kbk, En, KCOEF);
  dim3 gv(Mtok / 64, En / 128);  // x=col-block (128), y=row-block (4)
  gemm_bt_relu<1, 0><<<gv, 256, 0, stream>>>(wvb, x2b, bv, vtb, Mtok, 1.0f);

  dim3 ga(Bb * Hn, LQn / 64);  // x=bh (64), y=qblk (16)
  attn_kernel<<<ga, 256, 0, stream>>>(qbq, kbk, vtb, kmask, qmask, out);
}